// Round 15
// baseline (226.389 us; speedup 1.0000x reference)
//
#include <hip/hip_runtime.h>
#include <hip/hip_bf16.h>

#define NSUBJ 64
#define CIN   295
#define DD    270
#define TT    2048
#define BB    128

// Wf tiled layout: [s][ks:10][kq:4][m:288][k8:8]  (bf16, c = ks*32+kq*8+k8)
// column c==295 holds the fused bias (Ws@b1); B-side c==295 synthesized as 1.0
#define WF_PER_S  92160   // 10*4*288*8
#define WF_PER_KS 9216    // 4*288*8
// W1t tiled layout: [ks:9][kq:4][c:320][8] bf16 (d = ks*32+kq*8+k8), c=295 -> b1
#define W1T_PER_KS 10240  // 4*320*8

typedef __attribute__((ext_vector_type(8))) short bf16x8;
typedef __attribute__((ext_vector_type(4))) float f32x4;
typedef unsigned short u16;

__device__ __forceinline__ u16 f2bf(float f) {
    return __bfloat16_as_ushort(__float2bfloat16(f));   // RNE HW cvt
}

// async global->LDS, 16B/lane; lds dest = base + lane*16 (linear, wave-uniform base)
__device__ __forceinline__ void glds16(const void* g, void* lds_base) {
    __builtin_amdgcn_global_load_lds(
        (const __attribute__((address_space(1))) unsigned int*)g,
        (__attribute__((address_space(3))) unsigned int*)lds_base, 16, 0, 0);
}

#define WAITV(N) asm volatile("s_waitcnt vmcnt(" #N ")" ::: "memory")
#define SB()     __builtin_amdgcn_sched_barrier(0)

// ---------------------------------------------------------------------------
// W1 [270][295] f32 (+ b1 as c=295) -> W1t bf16 tiled [ks][kq][c:320][8]
// ---------------------------------------------------------------------------
__global__ __launch_bounds__(256) void k_prep_w1(const float* __restrict__ W1,
                                                 const float* __restrict__ b1,
                                                 u16* __restrict__ W1t)
{
    const int idx = blockIdx.x * 256 + threadIdx.x;      // 92160 total
    const int ks = idx / W1T_PER_KS;
    const int r  = idx - ks * W1T_PER_KS;
    const int kq = r / 2560;
    const int c  = (r - kq * 2560) >> 3;   // 0..319
    const int k8 = r & 7;
    const int d  = ks * 32 + kq * 8 + k8;
    float v = 0.f;
    if (d < DD) {
        if (c < CIN) v = W1[d * CIN + c];
        else if (c == CIN) v = b1[d];
    }
    W1t[idx] = f2bf(v);
}

// ---------------------------------------------------------------------------
// Wf[s] = bf16(Ws[s] @ [W1|b1]) in k_main's tiled A layout
// grid (3 mt, 64 s), block 256 = 4 waves (2M x 2N), tile 96e x 320c, K=288
// ---------------------------------------------------------------------------
__global__ __launch_bounds__(256, 1) void k_fuse_w(const float* __restrict__ Ws,
                                                   const u16* __restrict__ W1t,
                                                   u16* __restrict__ Wf)
{
    __shared__ u16 Aw[3072];    // [kq:4][96][8]
    __shared__ u16 Bw[10240];   // [kq:4][320][8]
    const int tid = threadIdx.x, lane = tid & 63, wid = tid >> 6;
    const int wm = wid >> 1, wn = wid & 1;
    const int mt = blockIdx.x, s = blockIdx.y;
    const int e0 = mt * 96;
    const float* Wsb = Ws + (size_t)s * DD * DD;

    f32x4 acc[3][10];
#pragma unroll
    for (int i = 0; i < 3; ++i)
#pragma unroll
        for (int j = 0; j < 10; ++j) acc[i][j] = (f32x4){0.f, 0.f, 0.f, 0.f};

    for (int ks = 0; ks < 9; ++ks) {
        const int k0 = ks * 32;
#pragma unroll
        for (int ci = 0; ci < 3; ++ci) {
            const int id = tid + ci * 256;
            const int m = id >> 3, q = id & 7;
            const int e = e0 + m, d = k0 + q * 4;
            float2 v01 = {0.f, 0.f}, v23 = {0.f, 0.f};
            if (e < DD) {
                if (d < DD)     v01 = *(const float2*)(Wsb + (size_t)e * DD + d);
                if (d + 2 < DD) v23 = *(const float2*)(Wsb + (size_t)e * DD + d + 2);
            }
            ushort4 h;
            h.x = f2bf(v01.x); h.y = f2bf(v01.y); h.z = f2bf(v23.x); h.w = f2bf(v23.y);
            *(ushort4*)(&Aw[(q >> 1) * 768 + m * 8 + (q & 1) * 4]) = h;
        }
#pragma unroll
        for (int k5 = 0; k5 < 5; ++k5) {
            const int seg = wid * 5 + k5;
            glds16(W1t + (size_t)ks * W1T_PER_KS + seg * 512 + lane * 8, &Bw[seg * 512]);
        }
        __syncthreads();
        bf16x8 af[3];
#pragma unroll
        for (int i = 0; i < 3; ++i)
            af[i] = *(const bf16x8*)(&Aw[(lane >> 4) * 768 + (wm * 48 + i * 16 + (lane & 15)) * 8]);
#pragma unroll
        for (int j = 0; j < 10; ++j) {
            const bf16x8 bfj = *(const bf16x8*)(&Bw[(lane >> 4) * 2560 + (wn * 160 + j * 16 + (lane & 15)) * 8]);
#pragma unroll
            for (int i = 0; i < 3; ++i)
                acc[i][j] = __builtin_amdgcn_mfma_f32_16x16x32_bf16(af[i], bfj, acc[i][j], 0, 0, 0);
        }
        __syncthreads();
    }
    const int rb = (lane >> 4) * 4, cc = lane & 15;
#pragma unroll
    for (int i = 0; i < 3; ++i) {
#pragma unroll
        for (int r = 0; r < 4; ++r) {
            const int e = e0 + wm * 48 + i * 16 + rb + r;
#pragma unroll
            for (int j = 0; j < 10; ++j) {
                const int c = wn * 160 + j * 16 + cc;
                Wf[(size_t)s * WF_PER_S + (c >> 5) * WF_PER_KS + ((c >> 3) & 3) * 2304
                   + e * 8 + (c & 7)] = f2bf(acc[i][j][r]);
            }
        }
    }
}

// ---------------------------------------------------------------------------
// out[b] = Wf[subj[b]] @ [X[b]; 1]
// ZERO-BARRIER k_main: each wave is fully self-sufficient.
//  - X: wave-private LDS quarter-tile [c:32][t:32] f32, 4 buffers (mod 4),
//    staged via glds16 with source-side t-XOR ((jj&1)<<4) => transposed
//    ds_read is 2-way bank-aliased (free).  4 glds x 1KB per step.
//  - A: direct-to-register from tiled Wf (L2-hot via XCD swizzle), double-
//    buffered 9x bf16x8, 9 dwordx4 per step, prefetched 1 step ahead.
//  - Per-wave FIFO vmcnt ladder (hand-simulated): steady WAITV(17) retires
//    exactly [X(k+1), A(k)]; X cover 3 steps, A cover 1 step. No s_barrier.
// grid 4096 XCD-chunked (512/XCD); block 256 = 4 waves (2M x 2N),
// tile 288e x 64t, K=320, fully unrolled.
// ---------------------------------------------------------------------------
__global__ __launch_bounds__(256, 2) void k_main(const float* __restrict__ X,
                                                 const int* __restrict__ subj,
                                                 const u16* __restrict__ Wf,
                                                 float* __restrict__ out)
{
    __shared__ float Xp[4][4][1024];  // [wave][buf][32c x 32t], 16KB/wave
    const int tid = threadIdx.x, lane = tid & 63, wid = tid >> 6;
    const int wm = wid >> 1, wn = wid & 1;
    const int g = lane >> 4, l15 = lane & 15;   // kq group 0..3
    const int hw = blockIdx.x;                  // 0..4095
    const int w  = (hw & 7) * 512 + (hw >> 3);  // bijection, 512 blocks/XCD
    const int b  = w >> 5, nt = w & 31;
    const int t0 = nt * 64;
    const int tw0 = t0 + wn * 32;               // this wave's 32 t-columns
    const int s = subj[b];
    const float* Xb = X + (size_t)b * CIN * TT;
    const u16* aB = Wf + (size_t)s * WF_PER_S + g * 2304 + (wm * 144 + l15) * 8;
    float* Xpw = &Xp[wid][0][0];

    f32x4 acc[9][2];
#pragma unroll
    for (int i = 0; i < 9; ++i)
#pragma unroll
        for (int j = 0; j < 2; ++j) acc[i][j] = (f32x4){0.f, 0.f, 0.f, 0.f};

    // X quarter-tile stage: 4 glds of 1KB. Lane covers tile row ct=8*jj+(l>>3),
    // dest t' = 4*(l&7); source t = t' ^ ((jj&1)<<4) (bank-spread swizzle).
#define STAGEXP(KS)                                                         \
    {                                                                       \
        _Pragma("unroll")                                                   \
        for (int jj = 0; jj < 4; ++jj) {                                    \
            const int ct  = jj * 8 + (lane >> 3);                           \
            const int cr0 = (KS) * 32 + ct;                                 \
            const int cr  = (cr0 < CIN) ? cr0 : (CIN - 1);                  \
            const int src = (4 * (lane & 7)) ^ ((jj & 1) << 4);             \
            glds16(Xb + (size_t)cr * TT + tw0 + src,                        \
                   Xpw + ((KS) & 3) * 1024 + jj * 256 + (lane & 7) * 4 + (lane >> 3) * 32); \
        }                                                                   \
    }
    // NOTE: glds dest must be wave-uniform base + lane*16B.  lane*16B in
    // floats = lane*4 = (lane>>3)*32 + (lane&7)*4  ✓ matches [ct][t'] layout.

    // A-frag register prefetch: 9 x dwordx4
#define LOADA(DST, KS)                                                      \
    {                                                                       \
        _Pragma("unroll")                                                   \
        for (int i = 0; i < 9; ++i)                                         \
            DST[i] = *(const bf16x8*)(aB + (size_t)(KS) * WF_PER_KS + i * 128); \
    }
    // B-frags from private tile (2-way banks) + MFMA with prefetched A
#define COMPUTE(KS, AF, LAST)                                               \
    {                                                                       \
        const float* Xc = Xpw + ((KS) & 3) * 1024;                          \
        bf16x8 bfr[2];                                                      \
        _Pragma("unroll")                                                   \
        for (int j = 0; j < 2; ++j) {                                       \
            bf16x8 bb;                                                      \
            _Pragma("unroll")                                               \
            for (int q = 0; q < 8; ++q) {                                   \
                const int tsw = (j * 16 + l15) ^ ((g & 1) << 4);            \
                float v = Xc[(g * 8 + q) * 32 + tsw];                       \
                if (LAST) {                                                 \
                    if (q == 7)      v = (g == 0) ? 1.0f : 0.0f;            \
                    else if (g > 0)  v = 0.0f;                              \
                }                                                           \
                bb[q] = (short)f2bf(v);                                     \
            }                                                               \
            bfr[j] = bb;                                                    \
        }                                                                   \
        _Pragma("unroll")                                                   \
        for (int i = 0; i < 9; ++i) {                                       \
            acc[i][0] = __builtin_amdgcn_mfma_f32_16x16x32_bf16(AF[i], bfr[0], acc[i][0], 0, 0, 0); \
            acc[i][1] = __builtin_amdgcn_mfma_f32_16x16x32_bf16(AF[i], bfr[1], acc[i][1], 0, 0, 0); \
        }                                                                   \
    }

    bf16x8 afE[9], afO[9];

    // ---- prologue: queue = [X0(4), A0(9), X1(4), X2(4)] = 21 ----
    STAGEXP(0);      SB();
    LOADA(afE, 0);   SB();
    STAGEXP(1);      SB();
    STAGEXP(2);      SB();

    // step 0: issue A1, X3; retire X0,A0 (13 of 34) -> WAITV(21)
    LOADA(afO, 1);   SB();
    STAGEXP(3);      SB();
    WAITV(21);       SB();
    COMPUTE(0, afE, 0);
    // step 1: issue A2, X4; retire X1,X2,A1 -> WAITV(17)
    LOADA(afE, 2);   SB();
    STAGEXP(4);      SB();
    WAITV(17);       SB();
    COMPUTE(1, afO, 0);
    // steps 2..6 steady: issue A(k+1), X(k+3); WAITV(17) retires [X(k+1),A(k)]
#define STEP(K, AFL, AFU)                                                   \
    LOADA(AFL, (K) + 1); SB();                                              \
    STAGEXP((K) + 3);    SB();                                              \
    WAITV(17);           SB();                                              \
    COMPUTE(K, AFU, 0);
    STEP(2, afO, afE)
    STEP(3, afE, afO)
    STEP(4, afO, afE)
    STEP(5, afE, afO)
    STEP(6, afO, afE)
#undef STEP
    // step 7: issue A8 only; retire X8,A7 -> WAITV(13)
    LOADA(afE, 8);   SB();
    WAITV(13);       SB();
    COMPUTE(7, afO, 0);
    // step 8: issue A9; retire X9,A8 -> WAITV(9)
    LOADA(afO, 9);   SB();
    WAITV(9);        SB();
    COMPUTE(8, afE, 0);
    // step 9: retire A9 -> WAITV(0); bias/pad column in-register
    WAITV(0);        SB();
    COMPUTE(9, afO, 1);

    // epilogue: C/D layout col=lane&15, row=(lane>>4)*4+reg (bias fused in K)
    const int rb = g * 4;
#pragma unroll
    for (int i = 0; i < 9; ++i) {
#pragma unroll
        for (int r = 0; r < 4; ++r) {
            const int e = wm * 144 + i * 16 + rb + r;
            if (e < DD) {
#pragma unroll
                for (int j = 0; j < 2; ++j) {
                    const int t = tw0 + j * 16 + l15;
                    out[((size_t)b * DD + e) * TT + t] = acc[i][j][r];
                }
            }
        }
    }
#undef STAGEXP
#undef LOADA
#undef COMPUTE
}

extern "C" void kernel_launch(void* const* d_in, const int* in_sizes, int n_in,
                              void* d_out, int out_size, void* d_ws, size_t ws_size,
                              hipStream_t stream) {
    const float* X    = (const float*)d_in[0];
    const int*   subj = (const int*)d_in[1];
    const float* W1   = (const float*)d_in[2];
    const float* b1   = (const float*)d_in[3];
    const float* Ws   = (const float*)d_in[4];
    float* out = (float*)d_out;

    u16* Wf  = (u16*)d_ws;                                         // 11,796,480 B
    u16* W1t = (u16*)((char*)d_ws + (size_t)NSUBJ * WF_PER_S * 2); // + 184,320 B

    k_prep_w1<<<dim3(360), 256, 0, stream>>>(W1, b1, W1t);
    k_fuse_w<<<dim3(3, NSUBJ), 256, 0, stream>>>(Ws, W1t, Wf);
    k_main<<<dim3(TT / 64 * BB), 256, 0, stream>>>(X, subj, Wf, out);
}

// Round 16
// 194.924 us; speedup vs baseline: 1.1614x; 1.1614x over previous
//
#include <hip/hip_runtime.h>
#include <hip/hip_bf16.h>

#define NSUBJ 64
#define CIN   295
#define DD    270
#define TT    2048
#define BB    128

// Wf tiled layout: [s][ks:10][kq:4][m:288][k8:8]  (bf16, c = ks*32+kq*8+k8)
// column c==295 holds the fused bias (Ws@b1); B-side c==295 synthesized as 1.0
#define WF_PER_S  92160   // 10*4*288*8
#define WF_PER_KS 9216    // 4*288*8
// W1t tiled layout: [ks:9][kq:4][c:320][8] bf16 (d = ks*32+kq*8+k8), c=295 -> b1
#define W1T_PER_KS 10240  // 4*320*8

typedef __attribute__((ext_vector_type(8))) short bf16x8;
typedef __attribute__((ext_vector_type(4))) float f32x4;
typedef unsigned short u16;

__device__ __forceinline__ u16 f2bf(float f) {
    return __bfloat16_as_ushort(__float2bfloat16(f));   // RNE HW cvt
}

// async global->LDS, 16B/lane; lds dest = base + lane*16 (linear, wave-uniform base)
__device__ __forceinline__ void glds16(const void* g, void* lds_base) {
    __builtin_amdgcn_global_load_lds(
        (const __attribute__((address_space(1))) unsigned int*)g,
        (__attribute__((address_space(3))) unsigned int*)lds_base, 16, 0, 0);
}

#define WAITV(N) asm volatile("s_waitcnt vmcnt(" #N ")" ::: "memory")
#define BAR()    __builtin_amdgcn_s_barrier()
#define SB()     __builtin_amdgcn_sched_barrier(0)

// ---------------------------------------------------------------------------
// W1 [270][295] f32 (+ b1 as c=295) -> W1t bf16 tiled [ks][kq][c:320][8]
// ---------------------------------------------------------------------------
__global__ __launch_bounds__(256) void k_prep_w1(const float* __restrict__ W1,
                                                 const float* __restrict__ b1,
                                                 u16* __restrict__ W1t)
{
    const int idx = blockIdx.x * 256 + threadIdx.x;      // 92160 total
    const int ks = idx / W1T_PER_KS;
    const int r  = idx - ks * W1T_PER_KS;
    const int kq = r / 2560;
    const int c  = (r - kq * 2560) >> 3;   // 0..319
    const int k8 = r & 7;
    const int d  = ks * 32 + kq * 8 + k8;
    float v = 0.f;
    if (d < DD) {
        if (c < CIN) v = W1[d * CIN + c];
        else if (c == CIN) v = b1[d];
    }
    W1t[idx] = f2bf(v);
}

// ---------------------------------------------------------------------------
// Wf[s] = bf16(Ws[s] @ [W1|b1]) in k_main's tiled A layout
// grid (3 mt, 64 s), block 256 = 4 waves (2M x 2N), tile 96e x 320c, K=288
// ---------------------------------------------------------------------------
__global__ __launch_bounds__(256, 1) void k_fuse_w(const float* __restrict__ Ws,
                                                   const u16* __restrict__ W1t,
                                                   u16* __restrict__ Wf)
{
    __shared__ u16 Aw[3072];    // [kq:4][96][8]
    __shared__ u16 Bw[10240];   // [kq:4][320][8]
    const int tid = threadIdx.x, lane = tid & 63, wid = tid >> 6;
    const int wm = wid >> 1, wn = wid & 1;
    const int mt = blockIdx.x, s = blockIdx.y;
    const int e0 = mt * 96;
    const float* Wsb = Ws + (size_t)s * DD * DD;

    f32x4 acc[3][10];
#pragma unroll
    for (int i = 0; i < 3; ++i)
#pragma unroll
        for (int j = 0; j < 10; ++j) acc[i][j] = (f32x4){0.f, 0.f, 0.f, 0.f};

    for (int ks = 0; ks < 9; ++ks) {
        const int k0 = ks * 32;
#pragma unroll
        for (int ci = 0; ci < 3; ++ci) {
            const int id = tid + ci * 256;
            const int m = id >> 3, q = id & 7;
            const int e = e0 + m, d = k0 + q * 4;
            float2 v01 = {0.f, 0.f}, v23 = {0.f, 0.f};
            if (e < DD) {
                if (d < DD)     v01 = *(const float2*)(Wsb + (size_t)e * DD + d);
                if (d + 2 < DD) v23 = *(const float2*)(Wsb + (size_t)e * DD + d + 2);
            }
            ushort4 h;
            h.x = f2bf(v01.x); h.y = f2bf(v01.y); h.z = f2bf(v23.x); h.w = f2bf(v23.y);
            *(ushort4*)(&Aw[(q >> 1) * 768 + m * 8 + (q & 1) * 4]) = h;
        }
#pragma unroll
        for (int k5 = 0; k5 < 5; ++k5) {
            const int seg = wid * 5 + k5;
            glds16(W1t + (size_t)ks * W1T_PER_KS + seg * 512 + lane * 8, &Bw[seg * 512]);
        }
        __syncthreads();
        bf16x8 af[3];
#pragma unroll
        for (int i = 0; i < 3; ++i)
            af[i] = *(const bf16x8*)(&Aw[(lane >> 4) * 768 + (wm * 48 + i * 16 + (lane & 15)) * 8]);
#pragma unroll
        for (int j = 0; j < 10; ++j) {
            const bf16x8 bfj = *(const bf16x8*)(&Bw[(lane >> 4) * 2560 + (wn * 160 + j * 16 + (lane & 15)) * 8]);
#pragma unroll
            for (int i = 0; i < 3; ++i)
                acc[i][j] = __builtin_amdgcn_mfma_f32_16x16x32_bf16(af[i], bfj, acc[i][j], 0, 0, 0);
        }
        __syncthreads();
    }
    const int rb = (lane >> 4) * 4, cc = lane & 15;
#pragma unroll
    for (int i = 0; i < 3; ++i) {
#pragma unroll
        for (int r = 0; r < 4; ++r) {
            const int e = e0 + wm * 48 + i * 16 + rb + r;
#pragma unroll
            for (int j = 0; j < 10; ++j) {
                const int c = wn * 160 + j * 16 + cc;
                Wf[(size_t)s * WF_PER_S + (c >> 5) * WF_PER_KS + ((c >> 3) & 3) * 2304
                   + e * 8 + (c & 7)] = f2bf(acc[i][j][r]);
            }
        }
    }
}

// ---------------------------------------------------------------------------
// out[b] = Wf[subj[b]] @ [X[b]; 1]
// PHASE-SPLIT k_main (T3-lite + T5 on the R11 base):
//  Data paths identical to R11 (glds16-only staging, triple LDS buffer,
//  stage-2-ahead, src-swizzled X transpose, counted-vmcnt entry wait).
//  Each K-step = 2 phases:
//   P0: issue A-glds(k+2) | 9 A ds_reads + B0 build | BAR | prio1 9xMFMA prio0 | BAR
//   P1: issue X-glds(k+2) | B1 build               | BAR | prio1 9xMFMA prio0
//  Barriers create load-issuing vs MFMA-entering wave role split on each
//  SIMD; s_setprio arbitrates (m218b/m224 mechanism).
// grid 4096 XCD-chunked (512/XCD); block 256 = 4 waves (2M x 2N),
// tile 288e x 64t, K=320.  Per wave per step glds: A{5,5,4,4} + X 2.
// ---------------------------------------------------------------------------
__global__ __launch_bounds__(256, 2) void k_main(const float* __restrict__ X,
                                                 const int* __restrict__ subj,
                                                 const u16* __restrict__ Wf,
                                                 float* __restrict__ out)
{
    __shared__ u16   Am[3][9216];    // [kq:4][288][8] bf16, 18KB each
    __shared__ float Xm[3][2048];    // [c:32][t:64] f32 (swizzled), 8KB each
    const int tid = threadIdx.x, lane = tid & 63, wid = tid >> 6;
    const int wm = wid >> 1, wn = wid & 1;
    const int g = lane >> 4, l15 = lane & 15;   // kq group 0..3
    const int hw = blockIdx.x;                  // 0..4095
    const int w  = (hw & 7) * 512 + (hw >> 3);  // bijection, 512 blocks/XCD
    const int b  = w >> 5, nt = w & 31;
    const int t0 = nt * 64;
    const int s = subj[b];
    const float* Xb = X + (size_t)b * CIN * TT;
    const u16* WfA = Wf + (size_t)s * WF_PER_S;

    f32x4 acc[9][2];
#pragma unroll
    for (int i = 0; i < 9; ++i)
#pragma unroll
        for (int j = 0; j < 2; ++j) acc[i][j] = (f32x4){0.f, 0.f, 0.f, 0.f};

    // A: 18 segs x 1KB; waves 0,1: 5 glds; waves 2,3: 4 glds
#define STAGEA(KS)                                                          \
    {                                                                       \
        _Pragma("unroll")                                                   \
        for (int k5 = 0; k5 < 5; ++k5) {                                    \
            const int seg = wid + 4 * k5;                                   \
            if (seg < 18)                                                   \
                glds16(WfA + (size_t)(KS) * WF_PER_KS + seg * 512 + lane * 8,\
                       &Am[(KS) % 3][seg * 512]);                           \
        }                                                                   \
    }
    // X: 8 segs x 1KB (4 rows of 64 f32); wave w stages segs 2w, 2w+1.
    // Per-lane source col pre-swizzled (16B-chunk XOR); row clamped to <295.
#define STAGEX(KS)                                                          \
    {                                                                       \
        _Pragma("unroll")                                                   \
        for (int k2 = 0; k2 < 2; ++k2) {                                    \
            const int seg = wid * 2 + k2;                                   \
            const int cr0 = (KS) * 32 + seg * 4 + g;                        \
            const int cr  = (cr0 < CIN) ? cr0 : (CIN - 1);                  \
            const int sc  = l15 ^ (((seg >> 1) & 3) << 2);                  \
            glds16(Xb + (size_t)cr * TT + t0 + sc * 4,                      \
                   &Xm[(KS) % 3][seg * 256]);                               \
        }                                                                   \
    }
#define WAITSTEP()  { if (wid < 2) WAITV(7); else WAITV(6); }
#define ENTRY()     { WAITSTEP(); BAR(); SB(); }

#define READA(KS, AF)                                                       \
    _Pragma("unroll")                                                       \
    for (int i = 0; i < 9; ++i)                                             \
        AF[i] = *(const bf16x8*)(&Am[(KS) % 3][g * 2304 + (wm * 144 + i * 16 + l15) * 8]);
#define BUILDB(KS, J, DST, LAST)                                            \
    {                                                                       \
        const float* Xc = &Xm[(KS) % 3][0];                                 \
        const int tsw = (wn * 32 + (J) * 16 + l15) ^ (g << 4);              \
        bf16x8 bb;                                                          \
        _Pragma("unroll")                                                   \
        for (int q = 0; q < 8; ++q) {                                       \
            float v = Xc[(g * 8 + q) * 64 + tsw];                           \
            if (LAST) {                                                     \
                if (q == 7)      v = (g == 0) ? 1.0f : 0.0f;                \
                else if (g > 0)  v = 0.0f;                                  \
            }                                                               \
            bb[q] = (short)f2bf(v);                                         \
        }                                                                   \
        DST = bb;                                                           \
    }
#define MFMA9(J, AF, BF)                                                    \
    __builtin_amdgcn_s_setprio(1);                                          \
    _Pragma("unroll")                                                       \
    for (int i = 0; i < 9; ++i)                                             \
        acc[i][J] = __builtin_amdgcn_mfma_f32_16x16x32_bf16(AF[i], BF, acc[i][J], 0, 0, 0); \
    __builtin_amdgcn_s_setprio(0);

    // two-phase step; STG: stage S(K+2); LAST: bias/pad column handling
#define STEP2P(K, STG, LAST)                                                \
    {                                                                       \
        bf16x8 af[9], b0, b1;                                               \
        if (STG) { STAGEA((K) + 2); SB(); }                                 \
        READA(K, af); BUILDB(K, 0, b0, LAST);                               \
        BAR();                                                              \
        MFMA9(0, af, b0);                                                   \
        BAR();                                                              \
        if (STG) { STAGEX((K) + 2); SB(); }                                 \
        BUILDB(K, 1, b1, LAST);                                             \
        BAR();                                                              \
        MFMA9(1, af, b1);                                                   \
    }

    // ---- prologue: issue S0, S1; retire S0 (S1 crosses the barrier) ----
    STAGEA(0); STAGEX(0); SB();
    STAGEA(1); STAGEX(1); SB();
    WAITSTEP();
    BAR(); SB();

    STEP2P(0, 1, 0)
    ENTRY() STEP2P(1, 1, 0)
    ENTRY() STEP2P(2, 1, 0)
    ENTRY() STEP2P(3, 1, 0)
    ENTRY() STEP2P(4, 1, 0)
    ENTRY() STEP2P(5, 1, 0)
    ENTRY() STEP2P(6, 1, 0)
    ENTRY() STEP2P(7, 1, 0)
    ENTRY() STEP2P(8, 0, 0)          // S10 doesn't exist; queue = [S9]
    { WAITV(0); BAR(); SB(); }       // drain S9
    STEP2P(9, 0, 1)                  // bias/pad column in-register

    // epilogue: C/D layout col=lane&15, row=(lane>>4)*4+reg (bias fused in K)
    const int rb = g * 4;
#pragma unroll
    for (int i = 0; i < 9; ++i) {
#pragma unroll
        for (int r = 0; r < 4; ++r) {
            const int e = wm * 144 + i * 16 + rb + r;
            if (e < DD) {
#pragma unroll
                for (int j = 0; j < 2; ++j) {
                    const int t = t0 + wn * 32 + j * 16 + l15;
                    out[((size_t)b * DD + e) * TT + t] = acc[i][j][r];
                }
            }
        }
    }
#undef STAGEA
#undef STAGEX
#undef WAITSTEP
#undef ENTRY
#undef READA
#undef BUILDB
#undef MFMA9
#undef STEP2P
}

extern "C" void kernel_launch(void* const* d_in, const int* in_sizes, int n_in,
                              void* d_out, int out_size, void* d_ws, size_t ws_size,
                              hipStream_t stream) {
    const float* X    = (const float*)d_in[0];
    const int*   subj = (const int*)d_in[1];
    const float* W1   = (const float*)d_in[2];
    const float* b1   = (const float*)d_in[3];
    const float* Ws   = (const float*)d_in[4];
    float* out = (float*)d_out;

    u16* Wf  = (u16*)d_ws;                                         // 11,796,480 B
    u16* W1t = (u16*)((char*)d_ws + (size_t)NSUBJ * WF_PER_S * 2); // + 184,320 B

    k_prep_w1<<<dim3(360), 256, 0, stream>>>(W1, b1, W1t);
    k_fuse_w<<<dim3(3, NSUBJ), 256, 0, stream>>>(Ws, W1t, Wf);
    k_main<<<dim3(TT / 64 * BB), 256, 0, stream>>>(X, subj, Wf, out);
}